// Round 1
// baseline (280.897 us; speedup 1.0000x reference)
//
#include <hip/hip_runtime.h>
#include <math.h>

// Problem: B=8, L=512, H=768, T=9, HEADS=12, d=64
//   Q = hs@Wq + bq ; K = hs@Wk + bk  (M=4096, N=6912, K=768)
//   RoPE per 64-wide d-block (pairs 2e,2e+1 -> outputs e, e+32)
//   score[b,i,j,t] = (1/96) * sum_c Qr[b*512+i, t*768+c] * Kr[b*512+j, t*768+c]
// All matmuls in bf16 MFMA (threshold 9.88e-3 allows it; predicted err ~3e-3).

typedef __attribute__((ext_vector_type(4))) float f32x4;
typedef __attribute__((ext_vector_type(8))) __bf16 bf16x8;
typedef __attribute__((ext_vector_type(8))) unsigned short ushort8;

#define HH   768
#define NCOL 6912   // H*T
#define MROW 4096   // B*L
#define LL   512

static __device__ __forceinline__ unsigned short f2bf(float f) {
  unsigned int u = __float_as_uint(f);
  u += 0x7FFFu + ((u >> 16) & 1u);   // round-to-nearest-even
  return (unsigned short)(u >> 16);
}

static __device__ __forceinline__ void async16(const void* g, void* l) {
  // width-16 global->LDS DMA; LDS dest = wave-uniform base + lane*16
  __builtin_amdgcn_global_load_lds(
      (const __attribute__((address_space(1))) unsigned int*)g,
      (__attribute__((address_space(3))) unsigned int*)l, 16, 0, 0);
}

// ---------------- prep kernels ----------------

__global__ void k_conv_hs(const float4* __restrict__ in, ushort8* __restrict__ out) {
  int idx = blockIdx.x * 256 + threadIdx.x;     // 393216 threads, 8 floats each
  float4 a = in[idx * 2], b = in[idx * 2 + 1];
  ushort8 o;
  o[0] = f2bf(a.x); o[1] = f2bf(a.y); o[2] = f2bf(a.z); o[3] = f2bf(a.w);
  o[4] = f2bf(b.x); o[5] = f2bf(b.y); o[6] = f2bf(b.z); o[7] = f2bf(b.w);
  out[idx] = o;
}

// W (768 x 6912) f32  ->  Wt (6912 x 768) bf16   (tiled 32x32 via LDS)
__global__ void k_transpose(const float* __restrict__ Wq, const float* __restrict__ Wk,
                            unsigned short* __restrict__ Wtq, unsigned short* __restrict__ Wtk) {
  __shared__ float tile[32][33];
  const float* W = blockIdx.z ? Wk : Wq;
  unsigned short* Wt = blockIdx.z ? Wtk : Wtq;
  int n0 = blockIdx.x * 32, k0 = blockIdx.y * 32;
  int tx = threadIdx.x, ty0 = threadIdx.y;      // block (32,8)
#pragma unroll
  for (int j = 0; j < 4; ++j) {
    int ty = ty0 + j * 8;
    tile[ty][tx] = W[(size_t)(k0 + ty) * NCOL + n0 + tx];
  }
  __syncthreads();
#pragma unroll
  for (int j = 0; j < 4; ++j) {
    int ty = ty0 + j * 8;
    Wt[(size_t)(n0 + ty) * HH + k0 + tx] = f2bf(tile[tx][ty]);
  }
}

// sin/cos tables, fp64 on device once: ang = i * 10000^(-p/32), i<512, p<32
__global__ void k_tables(float* __restrict__ st, float* __restrict__ ct) {
  int idx = blockIdx.x * 256 + threadIdx.x;     // 16384
  int i = idx >> 5, p = idx & 31;
  double ang = (double)i * pow(10000.0, -(double)p / 32.0);
  st[idx] = (float)sin(ang);
  ct[idx] = (float)cos(ang);
}

// ---------------- GEMM1: Q/K projection + bias + RoPE -> bf16 ----------------
// 128x128 tile, 4 waves (2x2), wave = 64x64 = 4x4 frags of 16x16x32 bf16.
// LDS: staging A[128][32]bf16 (8KB) + B[128][32] (8KB), epilogue 64x132 f32 (33.8KB, aliased)

__global__ __launch_bounds__(256) void k_gemm_rope(
    const unsigned short* __restrict__ hsb,
    const unsigned short* __restrict__ Wtq, const unsigned short* __restrict__ Wtk,
    const float* __restrict__ bq, const float* __restrict__ bk,
    const float* __restrict__ st, const float* __restrict__ ct,
    unsigned short* __restrict__ Qr, unsigned short* __restrict__ Kr) {
  __shared__ __align__(16) char smem[33792];
  const unsigned short* Wt = blockIdx.z ? Wtk : Wtq;
  const float* bias = blockIdx.z ? bk : bq;
  unsigned short* outp = blockIdx.z ? Kr : Qr;
  const int m0 = blockIdx.y * 128, n0 = blockIdx.x * 128;
  const int tid = threadIdx.x;
  const int lane = tid & 63, wid = tid >> 6;
  const int wr = wid >> 1, wc = wid & 1;

  f32x4 acc[4][4] = {};

  const int r = tid >> 2, cc = (tid & 3) * 8;
  const unsigned short* gA0 = hsb + (size_t)(m0 + r) * HH + cc;
  const unsigned short* gA1 = gA0 + (size_t)64 * HH;
  const unsigned short* gB0 = Wt + (size_t)(n0 + r) * HH + cc;
  const unsigned short* gB1 = gB0 + (size_t)64 * HH;
  char* lb = smem;
  const int wbase = wid * 1024;
  const int aoff = (wr * 64 + (lane & 15)) * 64 + (lane >> 4) * 16;
  const int boff = (wc * 64 + (lane & 15)) * 64 + (lane >> 4) * 16;

  for (int kk = 0; kk < HH; kk += 32) {
    async16(gA0 + kk, lb + wbase);
    async16(gA1 + kk, lb + 4096 + wbase);
    async16(gB0 + kk, lb + 8192 + wbase);
    async16(gB1 + kk, lb + 12288 + wbase);
    __syncthreads();
    bf16x8 af[4], bfr[4];
#pragma unroll
    for (int mf = 0; mf < 4; ++mf) af[mf] = *(const bf16x8*)(lb + aoff + mf * 1024);
#pragma unroll
    for (int nf = 0; nf < 4; ++nf) bfr[nf] = *(const bf16x8*)(lb + 8192 + boff + nf * 1024);
#pragma unroll
    for (int mf = 0; mf < 4; ++mf)
#pragma unroll
      for (int nf = 0; nf < 4; ++nf)
        acc[mf][nf] = __builtin_amdgcn_mfma_f32_16x16x32_bf16(af[mf], bfr[nf], acc[mf][nf], 0, 0, 0);
    __syncthreads();
  }

  // Epilogue: two 64-row halves through LDS, apply bias + RoPE, store bf16.
  float* eps = (float*)smem;
#pragma unroll
  for (int h = 0; h < 2; ++h) {
    if (wr == h) {
#pragma unroll
      for (int mf = 0; mf < 4; ++mf)
#pragma unroll
        for (int nf = 0; nf < 4; ++nf) {
          int rl = mf * 16 + (lane >> 4) * 4;
          int col = wc * 64 + nf * 16 + (lane & 15);
#pragma unroll
          for (int q = 0; q < 4; ++q)
            eps[(rl + q) * 132 + col] = acc[mf][nf][q];
        }
    }
    __syncthreads();
#pragma unroll 4
    for (int itn = 0; itn < 32; ++itn) {
      int idx = itn * 256 + tid;
      int rowl = idx >> 7, col = idx & 127;
      int grow = m0 + h * 64 + rowl;
      int i = grow & (LL - 1);                    // position within sequence
      int e = col & 63, p = e & 31, blkb = col & 64;
      float2 v = *(const float2*)(eps + rowl * 132 + blkb + 2 * p);
      int cg = n0 + blkb + 2 * p;
      float x1 = v.x + bias[cg], x2 = v.y + bias[cg + 1];
      float sv = st[i * 32 + p], cv = ct[i * 32 + p];
      float val = (e < 32) ? (x1 * cv - x2 * sv) : (x2 * cv + x1 * sv);
      outp[(size_t)grow * NCOL + n0 + col] = f2bf(val);
    }
    __syncthreads();
  }
}

// ---------------- GEMM2: score = (1/96) * Qr . Kr^T per (b,t) ----------------
// grid 1152 = 8b * 9t * (4x4 tiles of 128). Swizzle keeps the 9 t-blocks of one
// (b,ij) region consecutive on one XCD so stride-9 output writes merge in L2.

__global__ __launch_bounds__(256) void k_gemm_score(
    const unsigned short* __restrict__ Qr, const unsigned short* __restrict__ Kr,
    float* __restrict__ out) {
  __shared__ __align__(16) char smem[16384];
  int wg = blockIdx.x;
  int swz = (wg & 7) * 144 + (wg >> 3);   // 1152/8 = 144 per XCD chunk
  int t = swz % 9;
  int r2 = swz / 9;
  int jt = r2 & 3, it = (r2 >> 2) & 3, b = r2 >> 4;
  const int tid = threadIdx.x;
  const int lane = tid & 63, wid = tid >> 6;
  const int wr = wid >> 1, wc = wid & 1;
  f32x4 acc[4][4] = {};
  const int r = tid >> 2, cc = (tid & 3) * 8;
  const unsigned short* gA0 = Qr + (size_t)(b * 512 + it * 128 + r) * NCOL + t * 768 + cc;
  const unsigned short* gA1 = gA0 + (size_t)64 * NCOL;
  const unsigned short* gB0 = Kr + (size_t)(b * 512 + jt * 128 + r) * NCOL + t * 768 + cc;
  const unsigned short* gB1 = gB0 + (size_t)64 * NCOL;
  char* lb = smem;
  const int wbase = wid * 1024;
  const int aoff = (wr * 64 + (lane & 15)) * 64 + (lane >> 4) * 16;
  const int boff = (wc * 64 + (lane & 15)) * 64 + (lane >> 4) * 16;

  for (int kk = 0; kk < HH; kk += 32) {
    async16(gA0 + kk, lb + wbase);
    async16(gA1 + kk, lb + 4096 + wbase);
    async16(gB0 + kk, lb + 8192 + wbase);
    async16(gB1 + kk, lb + 12288 + wbase);
    __syncthreads();
    bf16x8 af[4], bfr[4];
#pragma unroll
    for (int mf = 0; mf < 4; ++mf) af[mf] = *(const bf16x8*)(lb + aoff + mf * 1024);
#pragma unroll
    for (int nf = 0; nf < 4; ++nf) bfr[nf] = *(const bf16x8*)(lb + 8192 + boff + nf * 1024);
#pragma unroll
    for (int mf = 0; mf < 4; ++mf)
#pragma unroll
      for (int nf = 0; nf < 4; ++nf)
        acc[mf][nf] = __builtin_amdgcn_mfma_f32_16x16x32_bf16(af[mf], bfr[nf], acc[mf][nf], 0, 0, 0);
    __syncthreads();
  }

  const float SC = 0.125f / 12.0f;   // scale/HEADS = 64^-0.5 / 12
#pragma unroll
  for (int mf = 0; mf < 4; ++mf)
#pragma unroll
    for (int nf = 0; nf < 4; ++nf) {
      int i0 = it * 128 + wr * 64 + mf * 16 + (lane >> 4) * 4;
      int j = jt * 128 + wc * 64 + nf * 16 + (lane & 15);
#pragma unroll
      for (int q = 0; q < 4; ++q) {
        size_t o = ((size_t)(b * 512 + i0 + q) * 512 + j) * 9 + t;
        out[o] = acc[mf][nf][q] * SC;
      }
    }
}

// ---------------- launch ----------------

extern "C" void kernel_launch(void* const* d_in, const int* in_sizes, int n_in,
                              void* d_out, int out_size, void* d_ws, size_t ws_size,
                              hipStream_t stream) {
  const float* hs = (const float*)d_in[0];
  const float* Wq = (const float*)d_in[1];
  const float* bq = (const float*)d_in[2];
  const float* Wk = (const float*)d_in[3];
  const float* bk = (const float*)d_in[4];
  float* out = (float*)d_out;
  char* ws = (char*)d_ws;

  // ws layout (bytes): needs ~141 MB
  float* sintab = (float*)(ws);                        //  65536
  float* costab = (float*)(ws + 65536);                //  65536
  unsigned short* hsb = (unsigned short*)(ws + 131072);        // 6291456
  unsigned short* Wtq = (unsigned short*)(ws + 6422528);       // 10616832
  unsigned short* Wtk = (unsigned short*)(ws + 17039360);      // 10616832
  unsigned short* Qr  = (unsigned short*)(ws + 27656192);      // 56623104
  unsigned short* Kr  = (unsigned short*)(ws + 84279296);      // 56623104 -> end 140902400

  hipLaunchKernelGGL(k_conv_hs, dim3(1536), dim3(256), 0, stream,
                     (const float4*)hs, (ushort8*)hsb);
  hipLaunchKernelGGL(k_transpose, dim3(216, 24, 2), dim3(32, 8), 0, stream,
                     Wq, Wk, Wtq, Wtk);
  hipLaunchKernelGGL(k_tables, dim3(64), dim3(256), 0, stream, sintab, costab);
  hipLaunchKernelGGL(k_gemm_rope, dim3(54, 32, 2), dim3(256), 0, stream,
                     hsb, Wtq, Wtk, bq, bk, sintab, costab, Qr, Kr);
  hipLaunchKernelGGL(k_gemm_score, dim3(1152), dim3(256), 0, stream, Qr, Kr, out);
}

// Round 2
// 238.533 us; speedup vs baseline: 1.1776x; 1.1776x over previous
//
#include <hip/hip_runtime.h>
#include <math.h>

// Problem: B=8, L=512, H=768, T=9, HEADS=12, d=64
//   Q = hs@Wq + bq ; K = hs@Wk + bk  (M=4096, N=6912, K=768)
//   RoPE per 64-wide d-block (pairs 2e,2e+1 -> outputs e, e+32)
//   score[b,i,j,t] = (1/96) * sum_c Qr[b*512+i, t*768+c] * Kr[b*512+j, t*768+c]
// R1: in-register RoPE epilogue. Wt rows are PERMUTED so that within each
// 64-col head block, frag pair (0,1) holds orig cols (2e,2e+1) at e=lane&15
// and pair (2,3) at e=16+(lane&15). Epilogue rotates in registers, no LDS.

typedef __attribute__((ext_vector_type(4))) float f32x4;
typedef __attribute__((ext_vector_type(8))) __bf16 bf16x8;
typedef __attribute__((ext_vector_type(8))) unsigned short ushort8;

#define HH   768
#define NCOL 6912   // H*T
#define LL   512

static __device__ __forceinline__ unsigned short f2bf(float f) {
  unsigned int u = __float_as_uint(f);
  u += 0x7FFFu + ((u >> 16) & 1u);   // round-to-nearest-even
  return (unsigned short)(u >> 16);
}

static __device__ __forceinline__ void async16(const void* g, void* l) {
  __builtin_amdgcn_global_load_lds(
      (const __attribute__((address_space(1))) unsigned int*)g,
      (__attribute__((address_space(3))) unsigned int*)l, 16, 0, 0);
}

// ---------------- prep kernels ----------------

__global__ void k_conv_hs(const float4* __restrict__ in, ushort8* __restrict__ out) {
  int idx = blockIdx.x * 256 + threadIdx.x;
  float4 a = in[idx * 2], b = in[idx * 2 + 1];
  ushort8 o;
  o[0] = f2bf(a.x); o[1] = f2bf(a.y); o[2] = f2bf(a.z); o[3] = f2bf(a.w);
  o[4] = f2bf(b.x); o[5] = f2bf(b.y); o[6] = f2bf(b.z); o[7] = f2bf(b.w);
  out[idx] = o;
}

// W (768 x 6912) f32 -> Wt (6912 x 768) bf16, rows permuted for in-reg RoPE:
// within each 64-col block c: new row = ((c&1)<<4) | ((c>>5)<<5) | ((c&31)>>1)
__global__ void k_transpose(const float* __restrict__ Wq, const float* __restrict__ Wk,
                            unsigned short* __restrict__ Wtq, unsigned short* __restrict__ Wtk) {
  __shared__ float tile[32][33];
  const float* W = blockIdx.z ? Wk : Wq;
  unsigned short* Wt = blockIdx.z ? Wtk : Wtq;
  int n0 = blockIdx.x * 32, k0 = blockIdx.y * 32;
  int tx = threadIdx.x, ty0 = threadIdx.y;      // block (32,8)
#pragma unroll
  for (int j = 0; j < 4; ++j) {
    int ty = ty0 + j * 8;
    tile[ty][tx] = W[(size_t)(k0 + ty) * NCOL + n0 + tx];
  }
  __syncthreads();
#pragma unroll
  for (int j = 0; j < 4; ++j) {
    int ty = ty0 + j * 8;
    int n = n0 + ty;
    int c = n & 63;
    int gc = ((c & 1) << 4) | ((c >> 5) << 5) | ((c & 31) >> 1);
    int np = (n & ~63) | gc;
    Wt[(size_t)np * HH + k0 + tx] = f2bf(tile[tx][ty]);
  }
}

// interleaved (sin,cos) table: sc[i*32+p] = (sin, cos) of i * 10000^(-p/32)
__global__ void k_tables(float2* __restrict__ sc) {
  int idx = blockIdx.x * 256 + threadIdx.x;     // 16384
  int i = idx >> 5, p = idx & 31;
  double ang = (double)i * pow(10000.0, -(double)p / 32.0);
  sc[idx] = make_float2((float)sin(ang), (float)cos(ang));
}

// ---------------- GEMM1: Q/K projection + bias + RoPE -> bf16 ----------------
// 128x128 tile, 4 waves (2x2), 4x4 frags of 16x16x32 bf16. LDS = 16KB staging.

__global__ __launch_bounds__(256) void k_gemm_rope(
    const unsigned short* __restrict__ hsb,
    const unsigned short* __restrict__ Wtq, const unsigned short* __restrict__ Wtk,
    const float* __restrict__ bq, const float* __restrict__ bk,
    const float2* __restrict__ sc,
    unsigned short* __restrict__ Qr, unsigned short* __restrict__ Kr) {
  __shared__ __align__(16) char smem[16384];
  const unsigned short* Wt = blockIdx.z ? Wtk : Wtq;
  const float* bias = blockIdx.z ? bk : bq;
  unsigned short* outp = blockIdx.z ? Kr : Qr;
  const int m0 = blockIdx.y * 128, n0 = blockIdx.x * 128;
  const int tid = threadIdx.x;
  const int lane = tid & 63, wid = tid >> 6;
  const int wr = wid >> 1, wc = wid & 1;

  f32x4 acc[4][4] = {};

  const int r = tid >> 2, cc = (tid & 3) * 8;
  const unsigned short* gA0 = hsb + (size_t)(m0 + r) * HH + cc;
  const unsigned short* gA1 = gA0 + (size_t)64 * HH;
  const unsigned short* gB0 = Wt + (size_t)(n0 + r) * HH + cc;
  const unsigned short* gB1 = gB0 + (size_t)64 * HH;
  char* lb = smem;
  const int wbase = wid * 1024;
  const int aoff = (wr * 64 + (lane & 15)) * 64 + (lane >> 4) * 16;
  const int boff = (wc * 64 + (lane & 15)) * 64 + (lane >> 4) * 16;

  for (int kk = 0; kk < HH; kk += 32) {
    async16(gA0 + kk, lb + wbase);
    async16(gA1 + kk, lb + 4096 + wbase);
    async16(gB0 + kk, lb + 8192 + wbase);
    async16(gB1 + kk, lb + 12288 + wbase);
    __syncthreads();
    bf16x8 af[4], bfr[4];
#pragma unroll
    for (int mf = 0; mf < 4; ++mf) af[mf] = *(const bf16x8*)(lb + aoff + mf * 1024);
#pragma unroll
    for (int nf = 0; nf < 4; ++nf) bfr[nf] = *(const bf16x8*)(lb + 8192 + boff + nf * 1024);
#pragma unroll
    for (int mf = 0; mf < 4; ++mf)
#pragma unroll
      for (int nf = 0; nf < 4; ++nf)
        acc[mf][nf] = __builtin_amdgcn_mfma_f32_16x16x32_bf16(af[mf], bfr[nf], acc[mf][nf], 0, 0, 0);
    __syncthreads();
  }

  // In-register RoPE epilogue.
  // frag pair (0,1): x1 = orig col 2*e0, x2 = 2*e0+1, e0 = lane&15
  // frag pair (2,3): e1 = 16 + (lane&15)
  const int cA = n0 + wc * 64;          // 64-col head-block base
  const int e0 = lane & 15;
  const int e1 = 16 + e0;
  const float b1a = bias[cA + 2 * e0], b2a = bias[cA + 2 * e0 + 1];
  const float b1b = bias[cA + 2 * e1], b2b = bias[cA + 2 * e1 + 1];

#pragma unroll
  for (int mf = 0; mf < 4; ++mf) {
    const int rbase = m0 + wr * 64 + mf * 16 + (lane >> 4) * 4;
#pragma unroll
    for (int q = 0; q < 4; ++q) {
      const int grow = rbase + q;
      const int i = grow & (LL - 1);
      float2 s0 = sc[i * 32 + e0];
      float2 s1 = sc[i * 32 + e1];
      float x1 = acc[mf][0][q] + b1a, x2 = acc[mf][1][q] + b2a;
      float y1 = acc[mf][2][q] + b1b, y2 = acc[mf][3][q] + b2b;
      size_t ro = (size_t)grow * NCOL + cA;
      outp[ro + e0]      = f2bf(x1 * s0.y - x2 * s0.x);
      outp[ro + e0 + 32] = f2bf(x2 * s0.y + x1 * s0.x);
      outp[ro + e1]      = f2bf(y1 * s1.y - y2 * s1.x);
      outp[ro + e1 + 32] = f2bf(y2 * s1.y + y1 * s1.x);
    }
  }
}

// ---------------- GEMM2: score = (1/96) * Qr . Kr^T per (b,t) ----------------

__global__ __launch_bounds__(256) void k_gemm_score(
    const unsigned short* __restrict__ Qr, const unsigned short* __restrict__ Kr,
    float* __restrict__ out) {
  __shared__ __align__(16) char smem[16384];
  int wg = blockIdx.x;
  int swz = (wg & 7) * 144 + (wg >> 3);   // 1152/8 = 144 per XCD chunk, t fastest
  int t = swz % 9;
  int r2 = swz / 9;
  int jt = r2 & 3, it = (r2 >> 2) & 3, b = r2 >> 4;
  const int tid = threadIdx.x;
  const int lane = tid & 63, wid = tid >> 6;
  const int wr = wid >> 1, wc = wid & 1;
  f32x4 acc[4][4] = {};
  const int r = tid >> 2, cc = (tid & 3) * 8;
  const unsigned short* gA0 = Qr + (size_t)(b * 512 + it * 128 + r) * NCOL + t * 768 + cc;
  const unsigned short* gA1 = gA0 + (size_t)64 * NCOL;
  const unsigned short* gB0 = Kr + (size_t)(b * 512 + jt * 128 + r) * NCOL + t * 768 + cc;
  const unsigned short* gB1 = gB0 + (size_t)64 * NCOL;
  char* lb = smem;
  const int wbase = wid * 1024;
  const int aoff = (wr * 64 + (lane & 15)) * 64 + (lane >> 4) * 16;
  const int boff = (wc * 64 + (lane & 15)) * 64 + (lane >> 4) * 16;

  for (int kk = 0; kk < HH; kk += 32) {
    async16(gA0 + kk, lb + wbase);
    async16(gA1 + kk, lb + 4096 + wbase);
    async16(gB0 + kk, lb + 8192 + wbase);
    async16(gB1 + kk, lb + 12288 + wbase);
    __syncthreads();
    bf16x8 af[4], bfr[4];
#pragma unroll
    for (int mf = 0; mf < 4; ++mf) af[mf] = *(const bf16x8*)(lb + aoff + mf * 1024);
#pragma unroll
    for (int nf = 0; nf < 4; ++nf) bfr[nf] = *(const bf16x8*)(lb + 8192 + boff + nf * 1024);
#pragma unroll
    for (int mf = 0; mf < 4; ++mf)
#pragma unroll
      for (int nf = 0; nf < 4; ++nf)
        acc[mf][nf] = __builtin_amdgcn_mfma_f32_16x16x32_bf16(af[mf], bfr[nf], acc[mf][nf], 0, 0, 0);
    __syncthreads();
  }

  const float SC = 0.125f / 12.0f;   // scale/HEADS = 64^-0.5 / 12
#pragma unroll
  for (int mf = 0; mf < 4; ++mf)
#pragma unroll
    for (int nf = 0; nf < 4; ++nf) {
      int i0 = it * 128 + wr * 64 + mf * 16 + (lane >> 4) * 4;
      int j = jt * 128 + wc * 64 + nf * 16 + (lane & 15);
#pragma unroll
      for (int q = 0; q < 4; ++q) {
        size_t o = ((size_t)(b * 512 + i0 + q) * 512 + j) * 9 + t;
        out[o] = acc[mf][nf][q] * SC;
      }
    }
}

// ---------------- launch ----------------

extern "C" void kernel_launch(void* const* d_in, const int* in_sizes, int n_in,
                              void* d_out, int out_size, void* d_ws, size_t ws_size,
                              hipStream_t stream) {
  const float* hs = (const float*)d_in[0];
  const float* Wq = (const float*)d_in[1];
  const float* bq = (const float*)d_in[2];
  const float* Wk = (const float*)d_in[3];
  const float* bk = (const float*)d_in[4];
  float* out = (float*)d_out;
  char* ws = (char*)d_ws;

  float2* sctab = (float2*)(ws);                               //  131072
  unsigned short* hsb = (unsigned short*)(ws + 131072);        // 6291456
  unsigned short* Wtq = (unsigned short*)(ws + 6422528);       // 10616832
  unsigned short* Wtk = (unsigned short*)(ws + 17039360);      // 10616832
  unsigned short* Qr  = (unsigned short*)(ws + 27656192);      // 56623104
  unsigned short* Kr  = (unsigned short*)(ws + 84279296);      // 56623104 -> end 140902400

  hipLaunchKernelGGL(k_conv_hs, dim3(1536), dim3(256), 0, stream,
                     (const float4*)hs, (ushort8*)hsb);
  hipLaunchKernelGGL(k_transpose, dim3(216, 24, 2), dim3(32, 8), 0, stream,
                     Wq, Wk, Wtq, Wtk);
  hipLaunchKernelGGL(k_tables, dim3(64), dim3(256), 0, stream, sctab);
  hipLaunchKernelGGL(k_gemm_rope, dim3(54, 32, 2), dim3(256), 0, stream,
                     hsb, Wtq, Wtk, bq, bk, sctab, Qr, Kr);
  hipLaunchKernelGGL(k_gemm_score, dim3(1152), dim3(256), 0, stream, Qr, Kr, out);
}